// Round 7
// baseline (131.738 us; speedup 1.0000x reference)
//
#include <hip/hip_runtime.h>
#include <hip/hip_bf16.h>
#include <math.h>

#define NQ 196
#define BATCH 4
#define HD 512            // H * D_K == D_MODEL
#define NH 8
#define DK 64
#define MROWS 784         // BATCH*NQ
#define MPAD 832          // 13*64: GEMM M-tile overhang rows

typedef __attribute__((ext_vector_type(8))) short short8;
typedef __attribute__((ext_vector_type(4))) short short4v;
typedef __attribute__((ext_vector_type(4))) float float4v;

__device__ __forceinline__ float b2f(short s) {
  return __uint_as_float(((unsigned)(unsigned short)s) << 16);
}
__device__ __forceinline__ short f2b(float x) {
  return __builtin_bit_cast(short, __float2bfloat16(x));
}
__device__ __forceinline__ float fexp2(float x) {
  float r; asm("v_exp_f32 %0, %1" : "=v"(r) : "v"(x)); return r;
}
__device__ __forceinline__ float frcp(float x) {
  float r; asm("v_rcp_f32 %0, %1" : "=v"(r) : "v"(x)); return r;
}
__device__ __forceinline__ void cvt4(float4 v, short4v& hi, short4v& lo) {
  float x[4] = {v.x, v.y, v.z, v.w};
  #pragma unroll
  for (int i = 0; i < 4; ++i) {
    hi[i] = f2b(x[i]);
    lo[i] = f2b(x[i] - b2f(hi[i]));
  }
}
__device__ __forceinline__ void cvt8(float4 v0, float4 v1, short8& hi, short8& lo) {
  short4v h0, l0, h1, l1;
  cvt4(v0, h0, l0); cvt4(v1, h1, l1);
  hi = short8{h0[0],h0[1],h0[2],h0[3],h1[0],h1[1],h1[2],h1[3]};
  lo = short8{l0[0],l0[1],l0[2],l0[3],l1[0],l1[1],l1[2],l1[3]};
}

// ==================== kernel 1: projections (q/k/v) =========================
// 64x64 tile, BK=64, A=X fp32, B=W fp32, both reg-staged->bf16 hi/lo.
// 2-deep register prefetch (two sets) + 2 LDS buffers: load(kt+2) issued at
// iter kt, staged at iter kt+1 -> load->use distance ~= 1 full round.
// Spare z==2 blocks also split Wo -> bf16 hi/lo for kernel 3.
struct ProjArgs {
  const float* X[3]; const float* W[3]; const float* bias[3];
  float* Cf[3]; short* Ch[3]; short* Cl[3];
  const float* Wo; short* Woh; short* Wol;
};

__global__ __launch_bounds__(512)
void proj_kernel(ProjArgs a) {
  const int z = blockIdx.z;
  const float* __restrict__ X = a.X[z];
  const float* __restrict__ W = a.W[z];
  const int t = threadIdx.x;
  const int ln = t & 63, lm = ln & 15, quad = ln >> 4;
  const int w = t >> 6, wm = w >> 1, wn = w & 1;
  const int m0 = blockIdx.x << 6, n0 = blockIdx.y << 6;

  __shared__ __align__(16) short smem[32768];   // 64 KB, 2 buffers x 32 KB

  const int sr = t >> 3;                       // staged row 0..63
  const int cg = (t & 7) << 3;                 // col group (8 floats)
  const int wIdx = sr * 64 + (cg ^ ((sr & 7) << 3));   // swizzled LDS slot
  const float* gA = X + (size_t)min(m0 + sr, MROWS - 1) * HD;   // clamp overhang
  const float* gB = W + (size_t)(n0 + sr) * HD;

  float4v acc0 = {0.f,0.f,0.f,0.f}, acc1 = {0.f,0.f,0.f,0.f};
  const int ar = (wm << 4) + lm;
  const int br0 = (wn << 5) + lm, br1 = br0 + 16;
  const int swz = (lm & 7) << 3;

  float4 a0A, a1A, b0A, b1A;    // register set A
  float4 a0B, a1B, b0B, b1B;    // register set B

#define PLOADA(T) do { const int kb = (T) << 6; \
    a0A = *(const float4*)(gA + kb + cg);  a1A = *(const float4*)(gA + kb + cg + 4); \
    b0A = *(const float4*)(gB + kb + cg);  b1A = *(const float4*)(gB + kb + cg + 4); } while(0)
#define PLOADB(T) do { const int kb = (T) << 6; \
    a0B = *(const float4*)(gA + kb + cg);  a1B = *(const float4*)(gA + kb + cg + 4); \
    b0B = *(const float4*)(gB + kb + cg);  b1B = *(const float4*)(gB + kb + cg + 4); } while(0)
#define PSTAGEA(BUF) do { short8 hi, lo; \
    cvt8(a0A, a1A, hi, lo); \
    *(short8*)&smem[(BUF) + 0    + wIdx] = hi;  *(short8*)&smem[(BUF) + 4096  + wIdx] = lo; \
    cvt8(b0A, b1A, hi, lo); \
    *(short8*)&smem[(BUF) + 8192 + wIdx] = hi;  *(short8*)&smem[(BUF) + 12288 + wIdx] = lo; } while(0)
#define PSTAGEB(BUF) do { short8 hi, lo; \
    cvt8(a0B, a1B, hi, lo); \
    *(short8*)&smem[(BUF) + 0    + wIdx] = hi;  *(short8*)&smem[(BUF) + 4096  + wIdx] = lo; \
    cvt8(b0B, b1B, hi, lo); \
    *(short8*)&smem[(BUF) + 8192 + wIdx] = hi;  *(short8*)&smem[(BUF) + 12288 + wIdx] = lo; } while(0)
#define PMFMA(BUF) do { const short* Sb = smem + (BUF); \
    _Pragma("unroll") \
    for (int h2 = 0; h2 < 2; ++h2) { \
      const int c = (h2 << 5) + (quad << 3); \
      const int cs = c ^ swz; \
      short8 a_h = *(const short8*)&Sb[         ar  * 64 + cs]; \
      short8 a_l = *(const short8*)&Sb[4096  +  ar  * 64 + cs]; \
      short8 b0h = *(const short8*)&Sb[8192  +  br0 * 64 + cs]; \
      short8 b0l = *(const short8*)&Sb[12288 +  br0 * 64 + cs]; \
      short8 b1h = *(const short8*)&Sb[8192  +  br1 * 64 + cs]; \
      short8 b1l = *(const short8*)&Sb[12288 +  br1 * 64 + cs]; \
      acc0 = __builtin_amdgcn_mfma_f32_16x16x32_bf16(a_h, b0h, acc0, 0,0,0); \
      acc0 = __builtin_amdgcn_mfma_f32_16x16x32_bf16(a_h, b0l, acc0, 0,0,0); \
      acc0 = __builtin_amdgcn_mfma_f32_16x16x32_bf16(a_l, b0h, acc0, 0,0,0); \
      acc1 = __builtin_amdgcn_mfma_f32_16x16x32_bf16(a_h, b1h, acc1, 0,0,0); \
      acc1 = __builtin_amdgcn_mfma_f32_16x16x32_bf16(a_h, b1l, acc1, 0,0,0); \
      acc1 = __builtin_amdgcn_mfma_f32_16x16x32_bf16(a_l, b1h, acc1, 0,0,0); \
    } } while(0)

  // prologue: tile0 -> set A -> buf0; tile1 -> set B (in flight)
  PLOADA(0);
  PSTAGEA(0);
  PLOADB(1);

  #pragma unroll
  for (int kk = 0; kk < 4; ++kk) {
    const int kt = kk << 1;
    // even iter kt: reads buf0; loads tile kt+2 -> A; stages B(kt+1) -> buf1
    __syncthreads();
    if (kt + 2 < 8) PLOADA(kt + 2);
    PMFMA(0);
    if (kt + 1 < 8) PSTAGEB(16384);
    // odd iter kt+1: reads buf1; loads tile kt+3 -> B; stages A(kt+2) -> buf0
    __syncthreads();
    if (kt + 3 < 8) PLOADB(kt + 3);
    PMFMA(16384);
    if (kt + 2 < 8) PSTAGEA(0);
  }
#undef PLOADA
#undef PLOADB
#undef PSTAGEA
#undef PSTAGEB
#undef PMFMA

  // epilogue: bias, fp32 store (+ bf16 hi/lo split for q/k)
  {
    const float* bias = a.bias[z];
    float* Cf = a.Cf[z]; short* Ch = a.Ch[z]; short* Cl = a.Cl[z];
    #pragma unroll
    for (int nf = 0; nf < 2; ++nf) {
      const float4v av = nf ? acc1 : acc0;
      const int n = n0 + (wn << 5) + (nf << 4) + lm;
      const float bv = bias[n];
      #pragma unroll
      for (int r = 0; r < 4; ++r) {
        const int m = m0 + (wm << 4) + (quad << 2) + r;   // < MPAD always
        const float c = av[r] + bv;
        Cf[(size_t)m * HD + n] = c;
        if (Ch) {
          const short hi = f2b(c);
          Ch[(size_t)m * HD + n] = hi;
          Cl[(size_t)m * HD + n] = f2b(c - b2f(hi));
        }
      }
    }
  }

  // Wo split (64 of the 104 z==2 blocks; independent of the GEMM above)
  if (z == 2) {
    const int lin = blockIdx.y * 13 + blockIdx.x;
    if (lin < 64) {
      const size_t off = (size_t)lin * 4096 + (size_t)t * 8;
      float4 v0 = *(const float4*)(a.Wo + off);
      float4 v1 = *(const float4*)(a.Wo + off + 4);
      short8 hi, lo; cvt8(v0, v1, hi, lo);
      *(short8*)(a.Woh + off) = hi;
      *(short8*)(a.Wol + off) = lo;
    }
  }
}

// ======== kernel 2: fused attention (scores MFMA + softmax + gated PV) ======
// One block per (q-tile 16, h, b); 8 waves. Phase 3: wave = (4 q-rows, k-half)
// -> R is only [2][16][64] (8 KB), LDS 21.3 KB -> 4 blocks/CU (wave-limited).
__global__ __launch_bounds__(512)
void attn_fused(const short* __restrict__ qsh, const short* __restrict__ qsl,
                const short* __restrict__ ksh, const short* __restrict__ ksl,
                const float* __restrict__ qsg, const float* __restrict__ kpg,
                const float* __restrict__ vpg, const float* __restrict__ scg,
                short* __restrict__ imgh, short* __restrict__ imgl) {
  const int q0 = blockIdx.x * 16;
  const int h  = blockIdx.y;
  const int b  = blockIdx.z;
  const int t  = threadIdx.x;
  const int w = t >> 6, ln = t & 63;
  const int lm = ln & 15, quad = ln >> 4;
  const float L2E = 1.4426950408889634f;

  __shared__ __align__(16) float S[16][212];  // 13.6 KB (16B-aligned rows)
  __shared__ float R2[2][16][64];             // 8 KB: k-half partials

  // ---- phase 1: S = q_sig . k_p^T (bf16x3 MFMA), waves stride nt by 8 ----
  const size_t abase = ((size_t)(b * NQ) + q0 + lm) * HD + h * DK + (quad << 3);
  short8 ah0 = *(const short8*)(qsh + abase);
  short8 ah1 = *(const short8*)(qsh + abase + 32);
  short8 al0 = *(const short8*)(qsl + abase);
  short8 al1 = *(const short8*)(qsl + abase + 32);

  for (int nt = w; nt < 13; nt += 8) {
    const size_t bbase = ((size_t)(b * NQ) + nt * 16 + lm) * HD + h * DK + (quad << 3);
    short8 bh0 = *(const short8*)(ksh + bbase);
    short8 bh1 = *(const short8*)(ksh + bbase + 32);
    short8 bl0 = *(const short8*)(ksl + bbase);
    short8 bl1 = *(const short8*)(ksl + bbase + 32);
    float4v acc = {0.f, 0.f, 0.f, 0.f};
    acc = __builtin_amdgcn_mfma_f32_16x16x32_bf16(ah0, bh0, acc, 0,0,0);
    acc = __builtin_amdgcn_mfma_f32_16x16x32_bf16(ah1, bh1, acc, 0,0,0);
    acc = __builtin_amdgcn_mfma_f32_16x16x32_bf16(ah0, bl0, acc, 0,0,0);
    acc = __builtin_amdgcn_mfma_f32_16x16x32_bf16(ah1, bl1, acc, 0,0,0);
    acc = __builtin_amdgcn_mfma_f32_16x16x32_bf16(al0, bh0, acc, 0,0,0);
    acc = __builtin_amdgcn_mfma_f32_16x16x32_bf16(al1, bh1, acc, 0,0,0);
    #pragma unroll
    for (int r = 0; r < 4; ++r)
      S[(quad << 2) + r][nt * 16 + lm] = acc[r];
  }
  __syncthreads();

  // ---- phase 2: softmax in place (wave w: rows 2w, 2w+1) ----
  for (int i = 0; i < 2; ++i) {
    const int rr = (w << 1) + i;
    const int q = q0 + rr;
    const bool qok = q < NQ;
    const float* srow = scg + ((size_t)h * NQ + (qok ? q : 0)) * NQ;
    float att[4];
    #pragma unroll
    for (int j = 0; j < 4; ++j) {
      const int c = ln + (j << 6);
      att[j] = -1e30f;
      if (c < NQ) att[j] = S[rr][c] * srow[c] * L2E;
    }
    float m = fmaxf(fmaxf(att[0], att[1]), fmaxf(att[2], att[3]));
    #pragma unroll
    for (int off = 32; off; off >>= 1) m = fmaxf(m, __shfl_xor(m, off, 64));
    float e[4], s = 0.f;
    #pragma unroll
    for (int j = 0; j < 4; ++j) { e[j] = fexp2(att[j] - m); s += e[j]; }
    #pragma unroll
    for (int off = 32; off; off >>= 1) s += __shfl_xor(s, off, 64);
    const float rinv = __fdividef(1.f, s);
    #pragma unroll
    for (int j = 0; j < 4; ++j) {
      const int c = ln + (j << 6);
      if (c < NQ) S[rr][c] = e[j] * rinv;
    }
  }
  __syncthreads();

  // ---- phase 3: gated PV. wave w -> q-rows (w>>1)*4..+3, k-half (w&1). ----
  // k ranges [0,100) and [100,196): 4-aligned so S reads stay ds_read_b128.
  {
    const int d = ln;
    const int qg = (w >> 1) << 2;               // 0,4,8,12
    const int kh = w & 1;
    const int kbeg = kh ? 100 : 0;
    const int kend = kh ? 196 : 100;
    const float LOG2E = 1.4426950408889634f;

    float nqs[4];
    #pragma unroll
    for (int qi = 0; qi < 4; ++qi) {
      const int row = min(b * NQ + q0 + qg + qi, MROWS - 1);  // clamp overhang
      nqs[qi] = -qsg[(size_t)row * HD + h * DK + d] * LOG2E;
    }
    const float* kp = kpg + ((size_t)(b * NQ)) * HD + h * DK + d;
    const float* vp = vpg + ((size_t)(b * NQ)) * HD + h * DK + d;

    float acc[4] = {0.f, 0.f, 0.f, 0.f};

    for (int k = kbeg; k < kend; k += 4) {
      const float kv0 = kp[(size_t)(k + 0) * HD];
      const float kv1 = kp[(size_t)(k + 1) * HD];
      const float kv2 = kp[(size_t)(k + 2) * HD];
      const float kv3 = kp[(size_t)(k + 3) * HD];
      const float vv0 = vp[(size_t)(k + 0) * HD];
      const float vv1 = vp[(size_t)(k + 1) * HD];
      const float vv2 = vp[(size_t)(k + 2) * HD];
      const float vv3 = vp[(size_t)(k + 3) * HD];
      #pragma unroll
      for (int qi = 0; qi < 4; ++qi) {
        const float4 s4 = *(const float4*)&S[qg + qi][k];
        acc[qi] += s4.x * (vv0 * frcp(1.f + fexp2(nqs[qi] * kv0)));
        acc[qi] += s4.y * (vv1 * frcp(1.f + fexp2(nqs[qi] * kv1)));
        acc[qi] += s4.z * (vv2 * frcp(1.f + fexp2(nqs[qi] * kv2)));
        acc[qi] += s4.w * (vv3 * frcp(1.f + fexp2(nqs[qi] * kv3)));
      }
    }
    #pragma unroll
    for (int qi = 0; qi < 4; ++qi) R2[kh][qg + qi][d] = acc[qi];
  }
  __syncthreads();

  // reduce the 2 k-halves, write image as bf16 hi/lo
  #pragma unroll
  for (int j = 0; j < 2; ++j) {
    const int idx = t + (j << 9);
    const int qi = idx >> 6, dd = idx & 63;
    const int q = q0 + qi;
    if (q < NQ) {
      const float s = R2[0][qi][dd] + R2[1][qi][dd];
      const size_t o = ((size_t)(b * NQ) + q) * HD + h * DK + dd;
      const short hi = f2b(s);
      imgh[o] = hi;
      imgl[o] = f2b(s - b2f(hi));
    }
  }
}

// ======== kernel 3: out = image @ Wo^T + bo, gated; 32x64 tile =============
// Register-staged bf16 (no gload_lds -> loads survive the barrier), 2-deep
// register prefetch + 2 LDS buffers (48 KB). 208 blocks.
__global__ __launch_bounds__(512)
void out_kernel(const short* __restrict__ Ahp, const short* __restrict__ Alp,
                const short* __restrict__ Bhp, const short* __restrict__ Blp,
                const float* __restrict__ bo, const float* __restrict__ q_sig,
                float* __restrict__ out) {
  __shared__ __align__(16) short smem[24576];  // 48 KB: 2 buf x {Ah2k Al2k Bh4k Bl4k}
  const int t = threadIdx.x;
  const int ln = t & 63, lm = ln & 15, quad = ln >> 4;
  const int w = t >> 6;
  const int wm = w >> 2, wn = w & 3;           // 2m x 4n waves, 16x16 out each
  const int m0 = blockIdx.x << 5, n0 = blockIdx.y << 6;

  // staging mapping:
  //  A: 256 threads per array (t<256 -> hi, else lo); row ra 0..31, col cga.
  //  B: 512 threads per array; row sr 0..63, col cgb; hi and lo both loaded.
  const int ra = (t & 255) >> 3;
  const int cga = (t & 7) << 3;
  const int aBase = (t < 256) ? 0 : 2048;            // Ah / Al (shorts)
  const int wIdxA = aBase + ra * 64 + (cga ^ ((ra & 7) << 3));
  const short* gAs = ((t < 256) ? Ahp : Alp) + (size_t)(m0 + ra) * HD + cga;

  const int sr = t >> 3;
  const int cgb = (t & 7) << 3;
  const int wIdxB = sr * 64 + (cgb ^ ((sr & 7) << 3));
  const short* gBh = Bhp + (size_t)(n0 + sr) * HD + cgb;
  const short* gBl = Blp + (size_t)(n0 + sr) * HD + cgb;

  const int ar = (wm << 4) + lm;                // A tile row (0..31)
  const int br = (wn << 4) + lm;                // B tile row (0..63)
  const int swz = (lm & 7) << 3;

  float4v acc = {0.f,0.f,0.f,0.f};
  short8 laA, lbhA, lblA, laB, lbhB, lblB;

#define OLOADA(T) do { const int kb = (T) << 6; \
    laA  = *(const short8*)(gAs + kb); \
    lbhA = *(const short8*)(gBh + kb); \
    lblA = *(const short8*)(gBl + kb); } while(0)
#define OLOADB(T) do { const int kb = (T) << 6; \
    laB  = *(const short8*)(gAs + kb); \
    lbhB = *(const short8*)(gBh + kb); \
    lblB = *(const short8*)(gBl + kb); } while(0)
#define OSTAGEA(BUF) do { \
    *(short8*)&smem[(BUF) + wIdxA] = laA; \
    *(short8*)&smem[(BUF) + 4096 + wIdxB] = lbhA; \
    *(short8*)&smem[(BUF) + 8192 + wIdxB] = lblA; } while(0)
#define OSTAGEB(BUF) do { \
    *(short8*)&smem[(BUF) + wIdxA] = laB; \
    *(short8*)&smem[(BUF) + 4096 + wIdxB] = lbhB; \
    *(short8*)&smem[(BUF) + 8192 + wIdxB] = lblB; } while(0)
#define OMFMA(BUF) do { const short* Sb = &smem[(BUF)]; \
    _Pragma("unroll") \
    for (int h2 = 0; h2 < 2; ++h2) { \
      const int c = (h2 << 5) + (quad << 3); \
      const int cs = c ^ swz; \
      short8 a_h = *(const short8*)&Sb[         ar * 64 + cs]; \
      short8 a_l = *(const short8*)&Sb[2048  +  ar * 64 + cs]; \
      short8 b_h = *(const short8*)&Sb[4096  +  br * 64 + cs]; \
      short8 b_l = *(const short8*)&Sb[8192  +  br * 64 + cs]; \
      acc = __builtin_amdgcn_mfma_f32_16x16x32_bf16(a_h, b_h, acc, 0,0,0); \
      acc = __builtin_amdgcn_mfma_f32_16x16x32_bf16(a_h, b_l, acc, 0,0,0); \
      acc = __builtin_amdgcn_mfma_f32_16x16x32_bf16(a_l, b_h, acc, 0,0,0); \
    } } while(0)

  // prologue: tile0 -> set A -> buf0; tile1 -> set B (in flight)
  OLOADA(0);
  OSTAGEA(0);
  OLOADB(1);

  #pragma unroll
  for (int kk = 0; kk < 4; ++kk) {
    const int kt = kk << 1;
    __syncthreads();
    if (kt + 2 < 8) OLOADA(kt + 2);
    OMFMA(0);
    if (kt + 1 < 8) OSTAGEB(12288);
    __syncthreads();
    if (kt + 3 < 8) OLOADB(kt + 3);
    OMFMA(12288);
    if (kt + 2 < 8) OSTAGEA(0);
  }
#undef OLOADA
#undef OLOADB
#undef OSTAGEA
#undef OSTAGEB
#undef OMFMA

  {
    const int n = n0 + (wn << 4) + lm;
    const float bv = bo[n];
    #pragma unroll
    for (int r = 0; r < 4; ++r) {
      const int m = m0 + (wm << 4) + (quad << 2) + r;
      if (m < MROWS) {
        float c = acc[r] + bv;
        const float qg = q_sig[(size_t)m * HD + n];
        c = __fdividef(c, 1.f + __expf(-qg * c));  // sigmoid(qg*c)*c
        out[(size_t)m * HD + n] = c;
      }
    }
  }
}

extern "C" void kernel_launch(void* const* d_in, const int* in_sizes, int n_in,
                              void* d_out, int out_size, void* d_ws, size_t ws_size,
                              hipStream_t stream) {
  const float* queries = (const float*)d_in[0];
  const float* keys    = (const float*)d_in[1];
  const float* values  = (const float*)d_in[2];
  const float* Wq = (const float*)d_in[3];
  const float* bq = (const float*)d_in[4];
  const float* Wk = (const float*)d_in[5];
  const float* bk = (const float*)d_in[6];
  const float* Wv = (const float*)d_in[7];
  const float* bv = (const float*)d_in[8];
  const float* Wo = (const float*)d_in[9];
  const float* bo = (const float*)d_in[10];
  const float* scale = (const float*)d_in[11];

  char* base = (char*)d_ws;
  const size_t NELPS = (size_t)MPAD * HD;    // 425984
  const size_t WEL   = (size_t)HD * HD;      // 262144

  size_t o = 0;
  float* q_sig = (float*)(base + o); o += NELPS * 4;
  float* k_p   = (float*)(base + o); o += NELPS * 4;
  float* v_p   = (float*)(base + o); o += NELPS * 4;
  short* qsh = (short*)(base + o); o += NELPS * 2;
  short* qsl = (short*)(base + o); o += NELPS * 2;
  short* ksh = (short*)(base + o); o += NELPS * 2;
  short* ksl = (short*)(base + o); o += NELPS * 2;
  short* imgh = (short*)(base + o); o += NELPS * 2;
  short* imgl = (short*)(base + o); o += NELPS * 2;
  short* Woh = (short*)(base + o); o += WEL * 2;
  short* Wol = (short*)(base + o); o += WEL * 2;

  // 1) projections + weight splits
  ProjArgs p;
  p.X[0] = queries; p.X[1] = keys; p.X[2] = values;
  p.W[0] = Wq;      p.W[1] = Wk;   p.W[2] = Wv;
  p.bias[0] = bq;   p.bias[1] = bk; p.bias[2] = bv;
  p.Cf[0] = q_sig;  p.Cf[1] = k_p;  p.Cf[2] = v_p;
  p.Ch[0] = qsh; p.Cl[0] = qsl;
  p.Ch[1] = ksh; p.Cl[1] = ksl;
  p.Ch[2] = nullptr; p.Cl[2] = nullptr;
  p.Wo = Wo; p.Woh = Woh; p.Wol = Wol;
  proj_kernel<<<dim3(MPAD/64, HD/64, 3), 512, 0, stream>>>(p);

  // 2) fused scores + softmax + gated PV -> image (bf16 hi/lo)
  attn_fused<<<dim3(13, NH, BATCH), 512, 0, stream>>>(
      qsh, qsl, ksh, ksl, q_sig, k_p, v_p, scale, imgh, imgl);

  // 3) out = image @ Wo^T + bo, gated by q_sig
  out_kernel<<<dim3(MPAD/32, HD/64), 512, 0, stream>>>(
      imgh, imgl, Woh, Wol, bo, q_sig, (float*)d_out);
}